// Round 19
// baseline (216.494 us; speedup 1.0000x reference)
//
#include <hip/hip_runtime.h>
#include <math.h>

#define NN 20000
#define EE 400000
#define FIN 256
#define HH 16
#define CC 32
#define HC 512    // channels per conv
#define H8W 1024  // h8 row width in bytes (conv1 | conv2)
#define HIDN 128
#define OUTC 32
#define WT 1024   // wtc rows (W1^T | W2^T)
#define GEMM_B 1256
#define TOT_B 1413   // 1256 conv-GEMM + 157 self

typedef unsigned short u16;
typedef unsigned char u8;
typedef __attribute__((ext_vector_type(8))) short short8v;
typedef __attribute__((ext_vector_type(4))) float f32x4;
typedef __attribute__((ext_vector_type(2))) float f32x2;

__device__ inline u16 f2bf(float f) {
  unsigned u = __builtin_bit_cast(unsigned, f);
  unsigned r = (u + 0x7fffu + ((u >> 16) & 1u)) >> 16;
  return (u16)r;
}

__device__ __forceinline__ void gload16(const u16* g, u16* l) {
  __builtin_amdgcn_global_load_lds(
      (const __attribute__((address_space(1))) unsigned int*)g,
      (__attribute__((address_space(3))) unsigned int*)l, 16, 0, 0);
}

// fp8 (e4m3) decode of 8 packed bytes -> packed-f32 fma into acc[0..4) (f32x2)
__device__ __forceinline__ void fp8x8_fma2(uint2 hv, float w, f32x2* acc) {
  f32x2 w2; w2.x = w; w2.y = w;
  f32x2 p0 = __builtin_amdgcn_cvt_pk_f32_fp8(hv.x, false);
  f32x2 p1 = __builtin_amdgcn_cvt_pk_f32_fp8(hv.x, true);
  f32x2 p2 = __builtin_amdgcn_cvt_pk_f32_fp8(hv.y, false);
  f32x2 p3 = __builtin_amdgcn_cvt_pk_f32_fp8(hv.y, true);
  acc[0] += p0 * w2;   // fp-contract -> v_pk_fma_f32
  acc[1] += p1 * w2;
  acc[2] += p2 * w2;
  acc[3] += p3 * w2;
}

// ------------------------------------------- merged converts + edge histogram
__global__ void k_prep_hist(const float* __restrict__ x, u16* __restrict__ xb,
                            const float* __restrict__ W1, const float* __restrict__ W2,
                            u16* __restrict__ wtc,
                            const float* __restrict__ L1, u16* __restrict__ lt1,
                            const float* __restrict__ L2, u16* __restrict__ lt2,
                            const int* __restrict__ ei, int* __restrict__ cur) {
  int b = blockIdx.x, t = threadIdx.x;
  if (b < 2500) {
    int i = b * 256 + t;
    float4 v0 = ((const float4*)x)[i * 2];
    float4 v1 = ((const float4*)x)[i * 2 + 1];
    short8v o;
    o[0] = (short)f2bf(v0.x); o[1] = (short)f2bf(v0.y);
    o[2] = (short)f2bf(v0.z); o[3] = (short)f2bf(v0.w);
    o[4] = (short)f2bf(v1.x); o[5] = (short)f2bf(v1.y);
    o[6] = (short)f2bf(v1.z); o[7] = (short)f2bf(v1.w);
    *(short8v*)(xb + (size_t)i * 8) = o;
  } else if (b < 3524) {
    int i = (b - 2500) * 256 + t;   // [1024][256]
    int n = i >> 8, k = i & 255;
    wtc[i] = f2bf(n < 512 ? W1[k * HC + n] : W2[k * HC + (n - 512)]);
  } else if (b < 3652) {
    int i = (b - 3524) * 256 + t;   // [128][256]
    int n = i >> 8, k = i & 255;
    lt1[i] = f2bf(L1[k * HIDN + n]);
  } else if (b < 3668) {
    int i = (b - 3652) * 256 + t;   // [32][128]
    int n = i >> 7, k = i & 127;
    lt2[i] = f2bf(L2[k * OUTC + n]);
  } else {
    int e = (b - 3668) * 256 + t;
    if (e < EE) {
      atomicAdd(&cur[ei[EE + e]], 1);       // conv1 aggregates at row1
      atomicAdd(&cur[NN + ei[e]], 1);       // conv2 aggregates at row0
    }
  }
}

__device__ void scan_one(int* cur, int* off, int* part) {
  const int t = threadIdx.x;
  const int CHK = 20;
  int base = t * CHK;
  int loc[CHK];
  int s = 0;
#pragma unroll
  for (int i = 0; i < CHK; ++i) {
    int idx = base + i;
    int v = (idx < NN) ? cur[idx] : 0;
    loc[i] = s;
    s += v;
  }
  part[t] = s;
  __syncthreads();
  for (int d = 1; d < 1024; d <<= 1) {
    int v2 = (t >= d) ? part[t - d] : 0;
    __syncthreads();
    part[t] += v2;
    __syncthreads();
  }
  int cbase = part[t] - s;
#pragma unroll
  for (int i = 0; i < CHK; ++i) {
    int idx = base + i;
    if (idx < NN) {
      int o = cbase + loc[i];
      off[idx] = o;
      cur[idx] = o;
    }
  }
  if (t == 1023) off[NN] = part[1023];
}

__global__ __launch_bounds__(1024) void k_scan(int* cur, int* off1, int* off2) {
  __shared__ int part[1024];
  if (blockIdx.x == 0) scan_one(cur, off1, part);
  else                 scan_one(cur + NN, off2, part);
}

// ------- mega kernel: { conv GEMM (h8 fp8 + a_s/a_d) | self MLP } + scatter EPILOGUE
// blocks [0,1256): conv GEMM (XCD-chunked); [1256,1413): self path.
// Scatter runs LAST so it overlaps with later blocks' GEMM compute.
__global__ __launch_bounds__(256) void k_gemm_big(const u16* __restrict__ A,
                                                  const u16* __restrict__ Bt,
                                                  const float* __restrict__ as1,
                                                  const float* __restrict__ ad1,
                                                  const float* __restrict__ as2,
                                                  const float* __restrict__ ad2,
                                                  u8* __restrict__ h8,
                                                  float* __restrict__ a_sA,
                                                  float* __restrict__ a_dA,
                                                  const int* __restrict__ ei,
                                                  int* __restrict__ cur,
                                                  int* __restrict__ adj1,
                                                  int* __restrict__ adj2,
                                                  const u16* __restrict__ lt1,
                                                  const u16* __restrict__ lt2,
                                                  const float* __restrict__ lin1_b,
                                                  const float* __restrict__ lin2_b,
                                                  float* __restrict__ out3) {
  __shared__ u16 smem[128 * 128];  // 32 KB both branches
  u16* As = smem;
  u16* Bs = smem + 128 * 64;
  const int hw = blockIdx.x;
  const int t = threadIdx.x;
  const int lane = t & 63, wave = t >> 6;
  const int wr = (wave >> 1) * 64, wc = (wave & 1) * 64;
  const int l15 = lane & 15, l4 = lane >> 4;
  const int rloc = lane >> 3;
  const int kc_src = (lane & 7) ^ rloc;
  const int K = FIN;

  if (hw < GEMM_B) {
    const int logical = (hw & 7) * 157 + (hw >> 3);
    const int bm = (logical >> 3) * 128, bn = logical & 7;

    f32x4 acc[4][4] = {};
    for (int k0 = 0; k0 < K; k0 += 64) {
      __syncthreads();
#pragma unroll
      for (int q = 0; q < 4; ++q) {
        const int rblk = q * 4 + wave;
        const int r = rblk * 8 + rloc;
        gload16(A + (size_t)(bm + r) * K + k0 + kc_src * 8, As + rblk * 512);
        gload16(Bt + (size_t)(bn * 128 + r) * K + k0 + kc_src * 8, Bs + rblk * 512);
      }
      __syncthreads();
#pragma unroll
      for (int kh = 0; kh < 2; ++kh) {
        const int kc = kh * 4 + l4;
        short8v af[4], bfr[4];
#pragma unroll
        for (int i = 0; i < 4; ++i) {
          int row = wr + i * 16 + l15;
          af[i] = *(const short8v*)(As + row * 64 + (kc ^ (row & 7)) * 8);
        }
#pragma unroll
        for (int j = 0; j < 4; ++j) {
          int row = wc + j * 16 + l15;
          bfr[j] = *(const short8v*)(Bs + row * 64 + (kc ^ (row & 7)) * 8);
        }
#pragma unroll
        for (int i = 0; i < 4; ++i)
#pragma unroll
          for (int j = 0; j < 4; ++j)
            acc[i][j] = __builtin_amdgcn_mfma_f32_16x16x32_bf16(af[i], bfr[j], acc[i][j], 0, 0, 0);
      }
    }

    const int conv = bn >> 2;
#pragma unroll
    for (int i = 0; i < 4; ++i)
#pragma unroll
      for (int j = 0; j < 4; ++j)
#pragma unroll
        for (int r = 0; r < 4; ++r) {
          int row = bm + wr + i * 16 + l4 * 4 + r;
          if (row >= NN) continue;
          int colb = bn * 128 + wc + j * 16 + l15;
          float v = acc[i][j][r];
          unsigned e8 = __builtin_amdgcn_cvt_pk_fp8_f32(v, v, 0, false);
          h8[(size_t)row * H8W + colb] = (u8)e8;
        }

    float asv[4], adv[4];
#pragma unroll
    for (int j = 0; j < 4; ++j) {
      int lc = (bn & 3) * 128 + wc + j * 16 + l15;
      int hh = lc >> 5, c = lc & 31;
      asv[j] = (conv ? as2 : as1)[hh * CC + c];
      adv[j] = (conv ? ad2 : ad1)[hh * CC + c];
    }
    const int hA = (bn & 3) * 4 + (wc >> 5);
    float* aS = a_sA + (size_t)conv * NN * HH;
    float* aD = a_dA + (size_t)conv * NN * HH;
#pragma unroll
    for (int i = 0; i < 4; ++i)
#pragma unroll
      for (int r = 0; r < 4; ++r) {
        float sAs = acc[i][0][r] * asv[0] + acc[i][1][r] * asv[1];
        float sAd = acc[i][0][r] * adv[0] + acc[i][1][r] * adv[1];
        float sBs = acc[i][2][r] * asv[2] + acc[i][3][r] * asv[3];
        float sBd = acc[i][2][r] * adv[2] + acc[i][3][r] * adv[3];
#pragma unroll
        for (int m = 1; m < 16; m <<= 1) {
          sAs += __shfl_xor(sAs, m);
          sAd += __shfl_xor(sAd, m);
          sBs += __shfl_xor(sBs, m);
          sBd += __shfl_xor(sBd, m);
        }
        int row = bm + wr + i * 16 + l4 * 4 + r;
        if (l15 == 0 && row < NN) {
          *(float2*)(aS + (size_t)row * HH + hA) = make_float2(sAs, sBs);
          *(float2*)(aD + (size_t)row * HH + hA) = make_float2(sAd, sBd);
        }
      }
  } else {
    // ---- self path: out3 = elu(elu(x@lin1+b)@lin2+b), 32 KB swizzled x1 tile
    const int bm = (hw - GEMM_B) * 128;
    f32x4 acc[4][4] = {};
    for (int k0 = 0; k0 < K; k0 += 64) {
      __syncthreads();
#pragma unroll
      for (int q = 0; q < 4; ++q) {
        const int rblk = q * 4 + wave;
        const int r = rblk * 8 + rloc;
        gload16(A + (size_t)(bm + r) * K + k0 + kc_src * 8, As + rblk * 512);
        gload16(lt1 + (size_t)r * K + k0 + kc_src * 8, Bs + rblk * 512);
      }
      __syncthreads();
#pragma unroll
      for (int kh = 0; kh < 2; ++kh) {
        const int kc = kh * 4 + l4;
        short8v af[4], bfr[4];
#pragma unroll
        for (int i = 0; i < 4; ++i) {
          int row = wr + i * 16 + l15;
          af[i] = *(const short8v*)(As + row * 64 + (kc ^ (row & 7)) * 8);
        }
#pragma unroll
        for (int j = 0; j < 4; ++j) {
          int row = wc + j * 16 + l15;
          bfr[j] = *(const short8v*)(Bs + row * 64 + (kc ^ (row & 7)) * 8);
        }
#pragma unroll
        for (int i = 0; i < 4; ++i)
#pragma unroll
          for (int j = 0; j < 4; ++j)
            acc[i][j] = __builtin_amdgcn_mfma_f32_16x16x32_bf16(af[i], bfr[j], acc[i][j], 0, 0, 0);
      }
    }
    __syncthreads();
    // x1 tile: (row,col) -> smem[row*128 + ((col>>3 ^ (row&7))<<3) + (col&7)]
#pragma unroll
    for (int i = 0; i < 4; ++i)
#pragma unroll
      for (int j = 0; j < 4; ++j)
#pragma unroll
        for (int r = 0; r < 4; ++r) {
          int row = wr + i * 16 + l4 * 4 + r;
          int col = wc + j * 16 + l15;
          float v = acc[i][j][r] + lin1_b[col];
          v = v > 0.f ? v : (expf(v) - 1.f);
          smem[row * 128 + ((((col >> 3) ^ (row & 7))) << 3) + (col & 7)] = f2bf(v);
        }
    __syncthreads();
    f32x4 acc2[2][2] = {};
#pragma unroll
    for (int kk = 0; kk < 4; ++kk) {
      short8v af[2], bfr[2];
#pragma unroll
      for (int i = 0; i < 2; ++i) {
        int row2 = wave * 32 + i * 16 + l15;
        af[i] = *(const short8v*)(smem + row2 * 128 + (((kk * 4 + l4) ^ (row2 & 7)) << 3));
      }
#pragma unroll
      for (int j = 0; j < 2; ++j)
        bfr[j] = *(const short8v*)(lt2 + (size_t)(j * 16 + l15) * 128 + kk * 32 + l4 * 8);
#pragma unroll
      for (int i = 0; i < 2; ++i)
#pragma unroll
        for (int j = 0; j < 2; ++j)
          acc2[i][j] = __builtin_amdgcn_mfma_f32_16x16x32_bf16(af[i], bfr[j], acc2[i][j], 0, 0, 0);
    }
#pragma unroll
    for (int i = 0; i < 2; ++i)
#pragma unroll
      for (int j = 0; j < 2; ++j)
#pragma unroll
        for (int r = 0; r < 4; ++r) {
          int row = bm + wave * 32 + i * 16 + l4 * 4 + r;
          int col = j * 16 + l15;
          if (row < NN) {
            float v = acc2[i][j][r] + lin2_b[col];
            v = v > 0.f ? v : (expf(v) - 1.f);
            out3[(size_t)row * OUTC + col] = v;
          }
        }
  }

  // ---- scatter EPILOGUE (overlaps with later blocks' GEMM compute)
  for (int e = hw * 256 + t; e < EE; e += TOT_B * 256) {
    int s1 = ei[e], d1 = ei[EE + e];
    int p1 = atomicAdd(&cur[d1], 1);
    adj1[p1] = s1;                      // conv1: message source = row0
    int p2 = atomicAdd(&cur[NN + s1], 1);
    adj2[p2] = d1;                      // conv2: message source = row1
  }
}

// ---------------- single-pass softmax+aggregation (round-14, deduped alpha).
__global__ __launch_bounds__(256) void k_edge(const int* __restrict__ adj1,
                                              const int* __restrict__ off1,
                                              const int* __restrict__ adj2,
                                              const int* __restrict__ off2,
                                              const float* __restrict__ a_sA,
                                              const float* __restrict__ a_dA,
                                              const u8* __restrict__ h8,
                                              const float* __restrict__ b1,
                                              const float* __restrict__ b2,
                                              float* __restrict__ out) {
  const int wv = threadIdx.x >> 6, lane = threadIdx.x & 63;
  const int gid = blockIdx.x * 4 + wv;
  const int conv = gid >= NN;
  const int node = gid - conv * NN;
  const int* __restrict__ adj = conv ? adj2 : adj1;
  const int* __restrict__ off = conv ? off2 : off1;
  const float* __restrict__ a_s = a_sA + (size_t)conv * NN * HH;
  const float* __restrict__ a_d = a_dA + (size_t)conv * NN * HH;
  const float* __restrict__ bias = conv ? b2 : b1;
  float* __restrict__ outp = out + (size_t)conv * NN * OUTC;
  const int e0 = off[node], e1 = off[node + 1];

  const int ea = lane >> 4, hh = lane & 15;   // alpha layout
  const int h = lane >> 2, cg = lane & 3;     // aggregation layout
  const u8* hb = h8 + conv * HC + h * CC + cg * 8;
  const float adh = a_d[node * HH + hh];
  f32x2 acc0[4] = {}, acc1[4] = {};
  float den = 0.f;
  int p = e0;
  for (; p + 4 <= e1; p += 4) {
    int se = adj[p + ea];
    float al = a_s[se * HH + hh] + adh;
    al = al > 0.f ? al : 0.2f * al;
    float wgt = __expf(al);
    den += wgt;
    float w0 = __shfl(wgt, h);
    float w1 = __shfl(wgt, 16 + h);
    float w2 = __shfl(wgt, 32 + h);
    float w3 = __shfl(wgt, 48 + h);
    int s0 = adj[p], s1 = adj[p + 1], s2 = adj[p + 2], s3 = adj[p + 3];
    uint2 h0 = *(const uint2*)(hb + (size_t)s0 * H8W);
    uint2 h1 = *(const uint2*)(hb + (size_t)s1 * H8W);
    uint2 h2v = *(const uint2*)(hb + (size_t)s2 * H8W);
    uint2 h3 = *(const uint2*)(hb + (size_t)s3 * H8W);
    fp8x8_fma2(h0, w0, acc0);
    fp8x8_fma2(h1, w1, acc1);
    fp8x8_fma2(h2v, w2, acc0);
    fp8x8_fma2(h3, w3, acc1);
  }
  if (p < e1) {  // tail: 1..3 edges
    int pe = p + ea;
    float wgt = 0.f;
    if (pe < e1) {
      int se = adj[pe];
      float al = a_s[se * HH + hh] + adh;
      al = al > 0.f ? al : 0.2f * al;
      wgt = __expf(al);
    }
    den += wgt;
    float w0 = __shfl(wgt, h);
    float w1 = __shfl(wgt, 16 + h);
    float w2 = __shfl(wgt, 32 + h);
    {
      int s0 = adj[p];
      uint2 h0 = *(const uint2*)(hb + (size_t)s0 * H8W);
      fp8x8_fma2(h0, w0, acc0);
    }
    if (p + 1 < e1) {
      int s1 = adj[p + 1];
      uint2 h1 = *(const uint2*)(hb + (size_t)s1 * H8W);
      fp8x8_fma2(h1, w1, acc1);
    }
    if (p + 2 < e1) {
      int s2 = adj[p + 2];
      uint2 h2v = *(const uint2*)(hb + (size_t)s2 * H8W);
      fp8x8_fma2(h2v, w2, acc0);
    }
  }
  den += __shfl_xor(den, 16);
  den += __shfl_xor(den, 32);
  float inv = (1.f / 16.f) / (den + 1e-16f);
  const float ivh = __shfl(inv, h);
  float accf[8];
#pragma unroll
  for (int i = 0; i < 4; ++i) {
    f32x2 s2v = acc0[i] + acc1[i];
    accf[2 * i] = s2v.x * ivh;
    accf[2 * i + 1] = s2v.y * ivh;
  }
#pragma unroll
  for (int mk = 4; mk <= 32; mk <<= 1)
#pragma unroll
    for (int i = 0; i < 8; ++i) accf[i] += __shfl_xor(accf[i], mk);
  if (lane < 4) {
#pragma unroll
    for (int i = 0; i < 8; ++i) {
      int c = cg * 8 + i;
      float v = accf[i] + bias[c];
      v = v > 0.f ? v : (expf(v) - 1.f);
      outp[(size_t)node * OUTC + c] = v;
    }
  }
}

// ---------------------------------------------------------------- launch
extern "C" void kernel_launch(void* const* d_in, const int* in_sizes, int n_in,
                              void* d_out, int out_size, void* d_ws, size_t ws_size,
                              hipStream_t stream) {
  const float* x = (const float*)d_in[0];
  const int* ei = (const int*)d_in[1];
  const float* W1 = (const float*)d_in[2];
  const float* att_src1 = (const float*)d_in[3];
  const float* att_dst1 = (const float*)d_in[4];
  const float* b1 = (const float*)d_in[5];
  const float* W2 = (const float*)d_in[6];
  const float* att_src2 = (const float*)d_in[7];
  const float* att_dst2 = (const float*)d_in[8];
  const float* b2 = (const float*)d_in[9];
  const float* lin1_w = (const float*)d_in[10];
  const float* lin1_b = (const float*)d_in[11];
  const float* lin2_w = (const float*)d_in[12];
  const float* lin2_b = (const float*)d_in[13];
  float* out = (float*)d_out;  // [x_in | x_out | x_self], each N*32

  char* w = (char*)d_ws;
  u8* h8 = (u8*)w;          w += (size_t)NN * H8W;           // 20.48 MB fp8
  u16* x_bf = (u16*)w;      w += (size_t)NN * FIN * 2;       // 10.24 MB
  u16* wtc = (u16*)w;       w += (size_t)WT * FIN * 2;       // 0.52 MB
  u16* lt1 = (u16*)w;       w += (size_t)HIDN * FIN * 2;
  u16* lt2 = (u16*)w;       w += (size_t)OUTC * HIDN * 2;
  float* a_sA = (float*)w;  w += (size_t)2 * NN * HH * 4;    // 2.56 MB
  float* a_dA = (float*)w;  w += (size_t)2 * NN * HH * 4;
  int* off1 = (int*)w;      w += (size_t)(NN + 1) * 4;
  int* off2 = (int*)w;      w += (size_t)(NN + 1) * 4;
  int* cur = (int*)w;       w += (size_t)2 * NN * 4;
  int* adj1 = (int*)w;      w += (size_t)EE * 4;
  int* adj2 = (int*)w;      w += (size_t)EE * 4;

  const int EB = (EE + 255) / 256;  // 1563

  // CSR histogram + converts
  hipMemsetAsync(cur, 0, (size_t)2 * NN * 4, stream);
  k_prep_hist<<<3668 + EB, 256, 0, stream>>>(x, x_bf, W1, W2, wtc, lin1_w, lt1,
                                             lin2_w, lt2, ei, cur);
  k_scan<<<2, 1024, 0, stream>>>(cur, off1, off2);

  // conv GEMM (h8 fp8 + fused a_s/a_d) + self path + scatter epilogue, one launch
  k_gemm_big<<<TOT_B, 256, 0, stream>>>(x_bf, wtc, att_src1, att_dst1,
                                        att_src2, att_dst2, h8, a_sA, a_dA,
                                        ei, cur, adj1, adj2, lt1, lt2,
                                        lin1_b, lin2_b,
                                        out + (size_t)2 * NN * OUTC);

  // single-pass softmax+aggregation, both convs
  k_edge<<<2 * (NN / 4), 256, 0, stream>>>(adj1, off1, adj2, off2, a_sA, a_dA,
                                           h8, b1, b2, out);
}

// Round 20
// 208.080 us; speedup vs baseline: 1.0404x; 1.0404x over previous
//
#include <hip/hip_runtime.h>
#include <math.h>

#define NN 20000
#define EE 400000
#define FIN 256
#define HH 16
#define CC 32
#define HC 512    // channels per conv
#define H8W 1024  // h8 row width in bytes (conv1 | conv2)
#define HIDN 128
#define OUTC 32
#define WT 1024   // wtc rows (W1^T | W2^T)
#define GEMM_B 1256
#define TOT_B 1413   // 1256 conv-GEMM + 157 self

typedef unsigned short u16;
typedef unsigned char u8;
typedef __attribute__((ext_vector_type(8))) short short8v;
typedef __attribute__((ext_vector_type(4))) float f32x4;
typedef __attribute__((ext_vector_type(2))) float f32x2;

__device__ inline u16 f2bf(float f) {
  unsigned u = __builtin_bit_cast(unsigned, f);
  unsigned r = (u + 0x7fffu + ((u >> 16) & 1u)) >> 16;
  return (u16)r;
}

__device__ __forceinline__ void gload16(const u16* g, u16* l) {
  __builtin_amdgcn_global_load_lds(
      (const __attribute__((address_space(1))) unsigned int*)g,
      (__attribute__((address_space(3))) unsigned int*)l, 16, 0, 0);
}

// fp8 (e4m3) decode of 8 packed bytes -> packed-f32 fma into acc[0..4) (f32x2)
__device__ __forceinline__ void fp8x8_fma2(uint2 hv, float w, f32x2* acc) {
  f32x2 w2; w2.x = w; w2.y = w;
  f32x2 p0 = __builtin_amdgcn_cvt_pk_f32_fp8(hv.x, false);
  f32x2 p1 = __builtin_amdgcn_cvt_pk_f32_fp8(hv.x, true);
  f32x2 p2 = __builtin_amdgcn_cvt_pk_f32_fp8(hv.y, false);
  f32x2 p3 = __builtin_amdgcn_cvt_pk_f32_fp8(hv.y, true);
  acc[0] += p0 * w2;   // fp-contract -> v_pk_fma_f32
  acc[1] += p1 * w2;
  acc[2] += p2 * w2;
  acc[3] += p3 * w2;
}

// ------------------------------------------- merged converts + edge histogram
__global__ void k_prep_hist(const float* __restrict__ x, u16* __restrict__ xb,
                            const float* __restrict__ W1, const float* __restrict__ W2,
                            u16* __restrict__ wtc,
                            const float* __restrict__ L1, u16* __restrict__ lt1,
                            const float* __restrict__ L2, u16* __restrict__ lt2,
                            const int* __restrict__ ei, int* __restrict__ cur) {
  int b = blockIdx.x, t = threadIdx.x;
  if (b < 2500) {
    int i = b * 256 + t;
    float4 v0 = ((const float4*)x)[i * 2];
    float4 v1 = ((const float4*)x)[i * 2 + 1];
    short8v o;
    o[0] = (short)f2bf(v0.x); o[1] = (short)f2bf(v0.y);
    o[2] = (short)f2bf(v0.z); o[3] = (short)f2bf(v0.w);
    o[4] = (short)f2bf(v1.x); o[5] = (short)f2bf(v1.y);
    o[6] = (short)f2bf(v1.z); o[7] = (short)f2bf(v1.w);
    *(short8v*)(xb + (size_t)i * 8) = o;
  } else if (b < 3524) {
    int i = (b - 2500) * 256 + t;   // [1024][256]
    int n = i >> 8, k = i & 255;
    wtc[i] = f2bf(n < 512 ? W1[k * HC + n] : W2[k * HC + (n - 512)]);
  } else if (b < 3652) {
    int i = (b - 3524) * 256 + t;   // [128][256]
    int n = i >> 8, k = i & 255;
    lt1[i] = f2bf(L1[k * HIDN + n]);
  } else if (b < 3668) {
    int i = (b - 3652) * 256 + t;   // [32][128]
    int n = i >> 7, k = i & 127;
    lt2[i] = f2bf(L2[k * OUTC + n]);
  } else {
    int e = (b - 3668) * 256 + t;
    if (e < EE) {
      atomicAdd(&cur[ei[EE + e]], 1);       // conv1 aggregates at row1
      atomicAdd(&cur[NN + ei[e]], 1);       // conv2 aggregates at row0
    }
  }
}

__device__ void scan_one(int* cur, int* off, int* part) {
  const int t = threadIdx.x;
  const int CHK = 20;
  int base = t * CHK;
  int loc[CHK];
  int s = 0;
#pragma unroll
  for (int i = 0; i < CHK; ++i) {
    int idx = base + i;
    int v = (idx < NN) ? cur[idx] : 0;
    loc[i] = s;
    s += v;
  }
  part[t] = s;
  __syncthreads();
  for (int d = 1; d < 1024; d <<= 1) {
    int v2 = (t >= d) ? part[t - d] : 0;
    __syncthreads();
    part[t] += v2;
    __syncthreads();
  }
  int cbase = part[t] - s;
#pragma unroll
  for (int i = 0; i < CHK; ++i) {
    int idx = base + i;
    if (idx < NN) {
      int o = cbase + loc[i];
      off[idx] = o;
      cur[idx] = o;
    }
  }
  if (t == 1023) off[NN] = part[1023];
}

__global__ __launch_bounds__(1024) void k_scan(int* cur, int* off1, int* off2) {
  __shared__ int part[1024];
  if (blockIdx.x == 0) scan_one(cur, off1, part);
  else                 scan_one(cur + NN, off2, part);
}

// ------- mega kernel: scatter stripe + { conv GEMM (h8 fp8 + a_s/a_d) | self MLP }
// blocks [0,1256): conv GEMM (XCD-chunked); [1256,1413): self path.
__global__ __launch_bounds__(256) void k_gemm_big(const u16* __restrict__ A,
                                                  const u16* __restrict__ Bt,
                                                  const float* __restrict__ as1,
                                                  const float* __restrict__ ad1,
                                                  const float* __restrict__ as2,
                                                  const float* __restrict__ ad2,
                                                  u8* __restrict__ h8,
                                                  float* __restrict__ a_sA,
                                                  float* __restrict__ a_dA,
                                                  const int* __restrict__ ei,
                                                  int* __restrict__ cur,
                                                  int* __restrict__ adj1,
                                                  int* __restrict__ adj2,
                                                  const u16* __restrict__ lt1,
                                                  const u16* __restrict__ lt2,
                                                  const float* __restrict__ lin1_b,
                                                  const float* __restrict__ lin2_b,
                                                  float* __restrict__ out3) {
  __shared__ u16 smem[128 * 128];  // 32 KB both branches
  u16* As = smem;
  u16* Bs = smem + 128 * 64;
  const int hw = blockIdx.x;
  const int t = threadIdx.x;
  const int lane = t & 63, wave = t >> 6;
  const int wr = (wave >> 1) * 64, wc = (wave & 1) * 64;
  const int l15 = lane & 15, l4 = lane >> 4;
  const int rloc = lane >> 3;
  const int kc_src = (lane & 7) ^ rloc;
  const int K = FIN;

  // ---- scatter stripe (all blocks; overlaps with GEMM wave-train)
  for (int e = hw * 256 + t; e < EE; e += TOT_B * 256) {
    int s1 = ei[e], d1 = ei[EE + e];
    int p1 = atomicAdd(&cur[d1], 1);
    adj1[p1] = s1;                      // conv1: message source = row0
    int p2 = atomicAdd(&cur[NN + s1], 1);
    adj2[p2] = d1;                      // conv2: message source = row1
  }

  if (hw < GEMM_B) {
    const int logical = (hw & 7) * 157 + (hw >> 3);
    const int bm = (logical >> 3) * 128, bn = logical & 7;

    f32x4 acc[4][4] = {};
    for (int k0 = 0; k0 < K; k0 += 64) {
      __syncthreads();
#pragma unroll
      for (int q = 0; q < 4; ++q) {
        const int rblk = q * 4 + wave;
        const int r = rblk * 8 + rloc;
        gload16(A + (size_t)(bm + r) * K + k0 + kc_src * 8, As + rblk * 512);
        gload16(Bt + (size_t)(bn * 128 + r) * K + k0 + kc_src * 8, Bs + rblk * 512);
      }
      __syncthreads();
#pragma unroll
      for (int kh = 0; kh < 2; ++kh) {
        const int kc = kh * 4 + l4;
        short8v af[4], bfr[4];
#pragma unroll
        for (int i = 0; i < 4; ++i) {
          int row = wr + i * 16 + l15;
          af[i] = *(const short8v*)(As + row * 64 + (kc ^ (row & 7)) * 8);
        }
#pragma unroll
        for (int j = 0; j < 4; ++j) {
          int row = wc + j * 16 + l15;
          bfr[j] = *(const short8v*)(Bs + row * 64 + (kc ^ (row & 7)) * 8);
        }
#pragma unroll
        for (int i = 0; i < 4; ++i)
#pragma unroll
          for (int j = 0; j < 4; ++j)
            acc[i][j] = __builtin_amdgcn_mfma_f32_16x16x32_bf16(af[i], bfr[j], acc[i][j], 0, 0, 0);
      }
    }

    const int conv = bn >> 2;
#pragma unroll
    for (int i = 0; i < 4; ++i)
#pragma unroll
      for (int j = 0; j < 4; ++j)
#pragma unroll
        for (int r = 0; r < 4; ++r) {
          int row = bm + wr + i * 16 + l4 * 4 + r;
          if (row >= NN) continue;
          int colb = bn * 128 + wc + j * 16 + l15;
          float v = acc[i][j][r];
          unsigned e8 = __builtin_amdgcn_cvt_pk_fp8_f32(v, v, 0, false);
          h8[(size_t)row * H8W + colb] = (u8)e8;
        }

    float asv[4], adv[4];
#pragma unroll
    for (int j = 0; j < 4; ++j) {
      int lc = (bn & 3) * 128 + wc + j * 16 + l15;
      int hh = lc >> 5, c = lc & 31;
      asv[j] = (conv ? as2 : as1)[hh * CC + c];
      adv[j] = (conv ? ad2 : ad1)[hh * CC + c];
    }
    const int hA = (bn & 3) * 4 + (wc >> 5);
    float* aS = a_sA + (size_t)conv * NN * HH;
    float* aD = a_dA + (size_t)conv * NN * HH;
#pragma unroll
    for (int i = 0; i < 4; ++i)
#pragma unroll
      for (int r = 0; r < 4; ++r) {
        float sAs = acc[i][0][r] * asv[0] + acc[i][1][r] * asv[1];
        float sAd = acc[i][0][r] * adv[0] + acc[i][1][r] * adv[1];
        float sBs = acc[i][2][r] * asv[2] + acc[i][3][r] * asv[3];
        float sBd = acc[i][2][r] * adv[2] + acc[i][3][r] * adv[3];
#pragma unroll
        for (int m = 1; m < 16; m <<= 1) {
          sAs += __shfl_xor(sAs, m);
          sAd += __shfl_xor(sAd, m);
          sBs += __shfl_xor(sBs, m);
          sBd += __shfl_xor(sBd, m);
        }
        int row = bm + wr + i * 16 + l4 * 4 + r;
        if (l15 == 0 && row < NN) {
          *(float2*)(aS + (size_t)row * HH + hA) = make_float2(sAs, sBs);
          *(float2*)(aD + (size_t)row * HH + hA) = make_float2(sAd, sBd);
        }
      }
  } else {
    // ---- self path: out3 = elu(elu(x@lin1+b)@lin2+b), 32 KB swizzled x1 tile
    const int bm = (hw - GEMM_B) * 128;
    f32x4 acc[4][4] = {};
    for (int k0 = 0; k0 < K; k0 += 64) {
      __syncthreads();
#pragma unroll
      for (int q = 0; q < 4; ++q) {
        const int rblk = q * 4 + wave;
        const int r = rblk * 8 + rloc;
        gload16(A + (size_t)(bm + r) * K + k0 + kc_src * 8, As + rblk * 512);
        gload16(lt1 + (size_t)r * K + k0 + kc_src * 8, Bs + rblk * 512);
      }
      __syncthreads();
#pragma unroll
      for (int kh = 0; kh < 2; ++kh) {
        const int kc = kh * 4 + l4;
        short8v af[4], bfr[4];
#pragma unroll
        for (int i = 0; i < 4; ++i) {
          int row = wr + i * 16 + l15;
          af[i] = *(const short8v*)(As + row * 64 + (kc ^ (row & 7)) * 8);
        }
#pragma unroll
        for (int j = 0; j < 4; ++j) {
          int row = wc + j * 16 + l15;
          bfr[j] = *(const short8v*)(Bs + row * 64 + (kc ^ (row & 7)) * 8);
        }
#pragma unroll
        for (int i = 0; i < 4; ++i)
#pragma unroll
          for (int j = 0; j < 4; ++j)
            acc[i][j] = __builtin_amdgcn_mfma_f32_16x16x32_bf16(af[i], bfr[j], acc[i][j], 0, 0, 0);
      }
    }
    __syncthreads();
    // x1 tile: (row,col) -> smem[row*128 + ((col>>3 ^ (row&7))<<3) + (col&7)]
#pragma unroll
    for (int i = 0; i < 4; ++i)
#pragma unroll
      for (int j = 0; j < 4; ++j)
#pragma unroll
        for (int r = 0; r < 4; ++r) {
          int row = wr + i * 16 + l4 * 4 + r;
          int col = wc + j * 16 + l15;
          float v = acc[i][j][r] + lin1_b[col];
          v = v > 0.f ? v : (expf(v) - 1.f);
          smem[row * 128 + ((((col >> 3) ^ (row & 7))) << 3) + (col & 7)] = f2bf(v);
        }
    __syncthreads();
    f32x4 acc2[2][2] = {};
#pragma unroll
    for (int kk = 0; kk < 4; ++kk) {
      short8v af[2], bfr[2];
#pragma unroll
      for (int i = 0; i < 2; ++i) {
        int row2 = wave * 32 + i * 16 + l15;
        af[i] = *(const short8v*)(smem + row2 * 128 + (((kk * 4 + l4) ^ (row2 & 7)) << 3));
      }
#pragma unroll
      for (int j = 0; j < 2; ++j)
        bfr[j] = *(const short8v*)(lt2 + (size_t)(j * 16 + l15) * 128 + kk * 32 + l4 * 8);
#pragma unroll
      for (int i = 0; i < 2; ++i)
#pragma unroll
        for (int j = 0; j < 2; ++j)
          acc2[i][j] = __builtin_amdgcn_mfma_f32_16x16x32_bf16(af[i], bfr[j], acc2[i][j], 0, 0, 0);
    }
#pragma unroll
    for (int i = 0; i < 2; ++i)
#pragma unroll
      for (int j = 0; j < 2; ++j)
#pragma unroll
        for (int r = 0; r < 4; ++r) {
          int row = bm + wave * 32 + i * 16 + l4 * 4 + r;
          int col = j * 16 + l15;
          if (row < NN) {
            float v = acc2[i][j][r] + lin2_b[col];
            v = v > 0.f ? v : (expf(v) - 1.f);
            out3[(size_t)row * OUTC + col] = v;
          }
        }
  }
}

// ---------------- single-pass softmax+aggregation (round-14, deduped alpha).
__global__ __launch_bounds__(256) void k_edge(const int* __restrict__ adj1,
                                              const int* __restrict__ off1,
                                              const int* __restrict__ adj2,
                                              const int* __restrict__ off2,
                                              const float* __restrict__ a_sA,
                                              const float* __restrict__ a_dA,
                                              const u8* __restrict__ h8,
                                              const float* __restrict__ b1,
                                              const float* __restrict__ b2,
                                              float* __restrict__ out) {
  const int wv = threadIdx.x >> 6, lane = threadIdx.x & 63;
  const int gid = blockIdx.x * 4 + wv;
  const int conv = gid >= NN;
  const int node = gid - conv * NN;
  const int* __restrict__ adj = conv ? adj2 : adj1;
  const int* __restrict__ off = conv ? off2 : off1;
  const float* __restrict__ a_s = a_sA + (size_t)conv * NN * HH;
  const float* __restrict__ a_d = a_dA + (size_t)conv * NN * HH;
  const float* __restrict__ bias = conv ? b2 : b1;
  float* __restrict__ outp = out + (size_t)conv * NN * OUTC;
  const int e0 = off[node], e1 = off[node + 1];

  const int ea = lane >> 4, hh = lane & 15;   // alpha layout
  const int h = lane >> 2, cg = lane & 3;     // aggregation layout
  const u8* hb = h8 + conv * HC + h * CC + cg * 8;
  const float adh = a_d[node * HH + hh];
  f32x2 acc0[4] = {}, acc1[4] = {};
  float den = 0.f;
  int p = e0;
  for (; p + 4 <= e1; p += 4) {
    int se = adj[p + ea];
    float al = a_s[se * HH + hh] + adh;
    al = al > 0.f ? al : 0.2f * al;
    float wgt = __expf(al);
    den += wgt;
    float w0 = __shfl(wgt, h);
    float w1 = __shfl(wgt, 16 + h);
    float w2 = __shfl(wgt, 32 + h);
    float w3 = __shfl(wgt, 48 + h);
    int s0 = adj[p], s1 = adj[p + 1], s2 = adj[p + 2], s3 = adj[p + 3];
    uint2 h0 = *(const uint2*)(hb + (size_t)s0 * H8W);
    uint2 h1 = *(const uint2*)(hb + (size_t)s1 * H8W);
    uint2 h2v = *(const uint2*)(hb + (size_t)s2 * H8W);
    uint2 h3 = *(const uint2*)(hb + (size_t)s3 * H8W);
    fp8x8_fma2(h0, w0, acc0);
    fp8x8_fma2(h1, w1, acc1);
    fp8x8_fma2(h2v, w2, acc0);
    fp8x8_fma2(h3, w3, acc1);
  }
  if (p < e1) {  // tail: 1..3 edges
    int pe = p + ea;
    float wgt = 0.f;
    if (pe < e1) {
      int se = adj[pe];
      float al = a_s[se * HH + hh] + adh;
      al = al > 0.f ? al : 0.2f * al;
      wgt = __expf(al);
    }
    den += wgt;
    float w0 = __shfl(wgt, h);
    float w1 = __shfl(wgt, 16 + h);
    float w2 = __shfl(wgt, 32 + h);
    {
      int s0 = adj[p];
      uint2 h0 = *(const uint2*)(hb + (size_t)s0 * H8W);
      fp8x8_fma2(h0, w0, acc0);
    }
    if (p + 1 < e1) {
      int s1 = adj[p + 1];
      uint2 h1 = *(const uint2*)(hb + (size_t)s1 * H8W);
      fp8x8_fma2(h1, w1, acc1);
    }
    if (p + 2 < e1) {
      int s2 = adj[p + 2];
      uint2 h2v = *(const uint2*)(hb + (size_t)s2 * H8W);
      fp8x8_fma2(h2v, w2, acc0);
    }
  }
  den += __shfl_xor(den, 16);
  den += __shfl_xor(den, 32);
  float inv = (1.f / 16.f) / (den + 1e-16f);
  const float ivh = __shfl(inv, h);
  float accf[8];
#pragma unroll
  for (int i = 0; i < 4; ++i) {
    f32x2 s2v = acc0[i] + acc1[i];
    accf[2 * i] = s2v.x * ivh;
    accf[2 * i + 1] = s2v.y * ivh;
  }
#pragma unroll
  for (int mk = 4; mk <= 32; mk <<= 1)
#pragma unroll
    for (int i = 0; i < 8; ++i) accf[i] += __shfl_xor(accf[i], mk);
  if (lane < 4) {
#pragma unroll
    for (int i = 0; i < 8; ++i) {
      int c = cg * 8 + i;
      float v = accf[i] + bias[c];
      v = v > 0.f ? v : (expf(v) - 1.f);
      outp[(size_t)node * OUTC + c] = v;
    }
  }
}

// ---------------------------------------------------------------- launch
extern "C" void kernel_launch(void* const* d_in, const int* in_sizes, int n_in,
                              void* d_out, int out_size, void* d_ws, size_t ws_size,
                              hipStream_t stream) {
  const float* x = (const float*)d_in[0];
  const int* ei = (const int*)d_in[1];
  const float* W1 = (const float*)d_in[2];
  const float* att_src1 = (const float*)d_in[3];
  const float* att_dst1 = (const float*)d_in[4];
  const float* b1 = (const float*)d_in[5];
  const float* W2 = (const float*)d_in[6];
  const float* att_src2 = (const float*)d_in[7];
  const float* att_dst2 = (const float*)d_in[8];
  const float* b2 = (const float*)d_in[9];
  const float* lin1_w = (const float*)d_in[10];
  const float* lin1_b = (const float*)d_in[11];
  const float* lin2_w = (const float*)d_in[12];
  const float* lin2_b = (const float*)d_in[13];
  float* out = (float*)d_out;  // [x_in | x_out | x_self], each N*32

  char* w = (char*)d_ws;
  u8* h8 = (u8*)w;          w += (size_t)NN * H8W;           // 20.48 MB fp8
  u16* x_bf = (u16*)w;      w += (size_t)NN * FIN * 2;       // 10.24 MB
  u16* wtc = (u16*)w;       w += (size_t)WT * FIN * 2;       // 0.52 MB
  u16* lt1 = (u16*)w;       w += (size_t)HIDN * FIN * 2;
  u16* lt2 = (u16*)w;       w += (size_t)OUTC * HIDN * 2;
  float* a_sA = (float*)w;  w += (size_t)2 * NN * HH * 4;    // 2.56 MB
  float* a_dA = (float*)w;  w += (size_t)2 * NN * HH * 4;
  int* off1 = (int*)w;      w += (size_t)(NN + 1) * 4;
  int* off2 = (int*)w;      w += (size_t)(NN + 1) * 4;
  int* cur = (int*)w;       w += (size_t)2 * NN * 4;
  int* adj1 = (int*)w;      w += (size_t)EE * 4;
  int* adj2 = (int*)w;      w += (size_t)EE * 4;

  const int EB = (EE + 255) / 256;  // 1563

  // CSR histogram + converts
  hipMemsetAsync(cur, 0, (size_t)2 * NN * 4, stream);
  k_prep_hist<<<3668 + EB, 256, 0, stream>>>(x, x_bf, W1, W2, wtc, lin1_w, lt1,
                                             lin2_w, lt2, ei, cur);
  k_scan<<<2, 1024, 0, stream>>>(cur, off1, off2);

  // scatter + conv GEMM (h8 fp8 + fused a_s/a_d) + self path, one launch
  k_gemm_big<<<TOT_B, 256, 0, stream>>>(x_bf, wtc, att_src1, att_dst1,
                                        att_src2, att_dst2, h8, a_sA, a_dA,
                                        ei, cur, adj1, adj2, lt1, lt2,
                                        lin1_b, lin2_b,
                                        out + (size_t)2 * NN * OUTC);

  // single-pass softmax+aggregation, both convs
  k_edge<<<2 * (NN / 4), 256, 0, stream>>>(adj1, off1, adj2, off2, a_sA, a_dA,
                                           h8, b1, b2, out);
}